// Round 10
// baseline (6694.263 us; speedup 1.0000x reference)
//
#include <hip/hip_runtime.h>
#include <cstdint>

// ---------------------------------------------------------------------------
// 2-layer LSTM encoder, B=32 T=512 F=H=1024.
// Phase 1: pack x, W0, U0, [W1;U1] into bf16 MFMA-fragment order.
// Phase 2: big GEMM xz0 = x @ W0 (bf16, fp32 accum), fragment-packed operands.
// Phase 3: persistent cooperative kernel, 256 WGs x 128 threads (2 waves).
//          ONE WAVE = ONE CHAIN (layer, batch-group). A-data staged via
//          global_load_lds (sc0|sc1 -> LLC-coherent) into per-wave LDS
//          buffers: deep pipelining with ZERO registers held per load.
//          Layer0: stage-all + single drain. Layer1: 16x4-kstep phases,
//          4KB dbuf, counted vmcnt(4) ladder. MFMA reads via plain ds_read.
//          h0/h1 in 8-deep rings; cross-WG data agent-scope sc1 (LLC).
// ---------------------------------------------------------------------------

typedef __attribute__((ext_vector_type(8))) short bf16x8;
typedef __attribute__((ext_vector_type(4))) float f32x4;
typedef __attribute__((ext_vector_type(2))) unsigned int u32x2;

// workspace layout (bytes)
#define XZ0_OFF   0ull                // 16384x4096 bf16   = 134217728
#define XF_OFF    134217728ull        // 16384x1024 bf16   =  33554432 (dead after gemm)
#define W0F_OFF   167772160ull        // 1024x4096  bf16   =   8388608
#define U0F_OFF   176160768ull        // 1024x4096  bf16   =   8388608
#define W1F_OFF   184549376ull        // 2048x4096  bf16   =  16777216
#define WS_TOTAL  201326592ull
// overlaid on XF after gemm_xw has consumed it:
#define RING_OFF  XF_OFF                  // h0 ring: 8 x 32x1024 bf16 = 524288
#define H1R_OFF   (XF_OFF + 524288ull)    // h1 ring: 8 x 32x1024 bf16 = 524288
#define FLG_OFF   (XF_OFF + 1048576ull)   // 4 x 128 u32 (l0g0,l0g1,l1g0,l1g1)

__device__ __forceinline__ float bf2f(short s) {
  unsigned int u = ((unsigned int)(unsigned short)s) << 16;
  return __builtin_bit_cast(float, u);
}
__device__ __forceinline__ short f2bf(float f) {
  unsigned int u = __builtin_bit_cast(unsigned int, f);
  u = (u + 0x7fffu + ((u >> 16) & 1u)) >> 16;   // RTNE
  return (short)u;
}
// plain (dispatch-boundary coherent) global->LDS, for weight fill
__device__ __forceinline__ void g2l16(const void* g, void* l) {
  __builtin_amdgcn_global_load_lds(
      (const __attribute__((address_space(1))) unsigned int*)g,
      (__attribute__((address_space(3))) unsigned int*)l, 16, 0, 0);
}
// coherent (sc0|sc1 = CPol GLC|SCC = 17) global->LDS: bypass L1/L2, read LLC
__device__ __forceinline__ void g2l16c(const void* g, void* l) {
  __builtin_amdgcn_global_load_lds(
      (const __attribute__((address_space(1))) unsigned int*)g,
      (__attribute__((address_space(3))) unsigned int*)l, 16, 0, 17);
}
__device__ __forceinline__ float sigm(float x) { return 1.f / (1.f + __expf(-x)); }

// agent-scope (LLC) access helpers — bypass per-XCD L2 staleness, no fences
__device__ __forceinline__ void st2_sc1(short* p, unsigned v) {
  asm volatile("global_store_short %0, %1, off sc1" :: "v"(p), "v"(v) : "memory");
}
__device__ __forceinline__ void st4_sc1(unsigned* p, unsigned v) {
  asm volatile("global_store_dword %0, %1, off sc1" :: "v"(p), "v"(v) : "memory");
}
#define VM_DRAIN asm volatile("s_waitcnt vmcnt(0)" ::: "memory")
#define VM_W4    asm volatile("s_waitcnt vmcnt(4)" ::: "memory")
#define SBAR __builtin_amdgcn_sched_barrier(0)

// ---------------------------------------------------------------------------
// pack_x: x fp32 [16384][1024] -> bf16 fragments [1024 mtiles][32 ksteps][64][8]
// ---------------------------------------------------------------------------
__global__ __launch_bounds__(256) void pack_x(const float* __restrict__ x,
                                              short* __restrict__ dst) {
  int gid = blockIdx.x * 256 + threadIdx.x;
  int lane = gid & 63;
  int unit = gid >> 6;
  int mtile = unit >> 5, kstep = unit & 31;
  int row = mtile * 16 + (lane & 15);
  int k0 = kstep * 32 + ((lane >> 4) << 3);
  const float* s = x + (size_t)row * 1024 + k0;
  bf16x8 v;
#pragma unroll
  for (int j = 0; j < 8; j++) v[j] = f2bf(s[j]);
  *(bf16x8*)(dst + (size_t)gid * 8) = v;
}

// ---------------------------------------------------------------------------
// pack_w: W fp32 [K][4096] -> bf16 fragments [256 ntiles][K/32][64][8]
// ---------------------------------------------------------------------------
__global__ __launch_bounds__(256) void pack_w(const float* __restrict__ src0,
                                              const float* __restrict__ src1,
                                              int ksh, short* __restrict__ dst) {
  int gid = blockIdx.x * 256 + threadIdx.x;
  int lane = gid & 63;
  int unit = gid >> 6;
  int ntile = unit >> ksh;
  int kstep = unit & ((1 << ksh) - 1);
  int col = ntile * 16 + (lane & 15);
  int k0 = kstep * 32 + ((lane >> 4) << 3);
  const float* s = (k0 < 1024) ? src0 : src1;
  int kk = k0 & 1023;
  bf16x8 v;
#pragma unroll
  for (int j = 0; j < 8; j++) v[j] = f2bf(s[(size_t)(kk + j) * 4096 + col]);
  *(bf16x8*)(dst + (size_t)gid * 8) = v;
}

// ---------------------------------------------------------------------------
// gemm_xw: xz0[16384][4096] = x @ W0  (bf16 in, fp32 accum, bf16 out)
// ---------------------------------------------------------------------------
__global__ __launch_bounds__(256) void gemm_xw(const short* __restrict__ xf,
                                               const short* __restrict__ wf,
                                               short* __restrict__ outz) {
  extern __shared__ char smem[];

  int bid = blockIdx.x;
  int swz = (bid & 7) * 512 + (bid >> 3);
  int bn = swz >> 7;
  int bm = swz & 127;

  const int tid = threadIdx.x, wid = tid >> 6, lane = tid & 63;
  const int wm = wid >> 1, wn = wid & 1;
  f32x4 acc[4][4] = {};

  const short* xbase = xf + (size_t)(bm * 8) * 32 * 512;
  const short* wbase = wf + (size_t)(bn * 8) * 32 * 512;

  auto Abuf = [&](int buf) -> short* { return (short*)(smem + buf * 32768); };
  auto Bbuf = [&](int buf) -> short* { return (short*)(smem + 16384 + buf * 32768); };

  auto stage = [&](int buf, int kt) {
    short* A = Abuf(buf);
    short* B = Bbuf(buf);
#pragma unroll
    for (int i = 0; i < 4; i++) {
      int u = wid + 4 * i;
      int mt = u >> 1, ks = u & 1;
      int gk = kt * 2 + ks;
      g2l16(xbase + (size_t)(mt * 32 + gk) * 512 + lane * 8, A + u * 512);
      g2l16(wbase + (size_t)(mt * 32 + gk) * 512 + lane * 8, B + u * 512);
    }
  };

  stage(0, 0);
  __syncthreads();
  for (int kt = 0; kt < 16; kt++) {
    int buf = kt & 1;
    if (kt < 15) stage(buf ^ 1, kt + 1);
    const short* A = Abuf(buf) + (wm * 4) * 1024;
    const short* B = Bbuf(buf) + (wn * 4) * 1024;
#pragma unroll
    for (int ks = 0; ks < 2; ks++) {
      bf16x8 av[4], bv[4];
#pragma unroll
      for (int i = 0; i < 4; i++) av[i] = *(const bf16x8*)(A + (i * 2 + ks) * 512 + lane * 8);
#pragma unroll
      for (int j = 0; j < 4; j++) bv[j] = *(const bf16x8*)(B + (j * 2 + ks) * 512 + lane * 8);
#pragma unroll
      for (int i = 0; i < 4; i++)
#pragma unroll
        for (int j = 0; j < 4; j++)
          acc[i][j] = __builtin_amdgcn_mfma_f32_16x16x32_bf16(av[i], bv[j], acc[i][j], 0, 0, 0);
    }
    __syncthreads();
  }

  int rb = bm * 128 + wm * 64 + ((lane >> 4) << 2);
  int cb = bn * 128 + wn * 64 + (lane & 15);
#pragma unroll
  for (int i = 0; i < 4; i++)
#pragma unroll
    for (int j = 0; j < 4; j++)
#pragma unroll
      for (int r = 0; r < 4; r++) {
        size_t row = rb + i * 16 + r;
        size_t col = cb + j * 16;
        outz[row * 4096 + col] = f2bf(acc[i][j][r]);
      }
}

// ---------------------------------------------------------------------------
// lstm_persist: one wave per (layer, group) chain; A staged through LDS.
// flags[4][128]: [l0g0][l0g1][l1g0][l1g1]
// LDS: l0 = weights 64K | Astage w0 32K | Astage w1 32K        (131072)
//      l1 = weights 128K | stage w0 2x4K | stage w1 2x4K       (147456)
// zb overlays own stage buffer (used only after compute drains).
// ---------------------------------------------------------------------------
__global__ __launch_bounds__(128, 1) void lstm_persist(
    const short* __restrict__ xz0, const short* __restrict__ u0f,
    const short* __restrict__ w1u1f, const float* __restrict__ b0,
    const float* __restrict__ b1, short* __restrict__ h0ring,
    short* __restrict__ h1ring, unsigned int* __restrict__ flags,
    float* __restrict__ out) {
  extern __shared__ char smem[];
  short* wlds = (short*)smem;                    // weight fragments (64/128KB)

  const int wg = blockIdx.x;
  const int tid = threadIdx.x;
  const int wid = tid >> 6;                      // wave = group g
  const int lane = tid & 63;
  const bool l1 = (wg >= 128);
  const int u0 = (wg & 127) * 8;
  const int KS = l1 ? 64 : 32;
  const int ksh = l1 ? 6 : 5;
  const short* wf = l1 ? w1u1f : u0f;
  short* Ast = l1 ? (short*)(smem + 131072 + wid * 8192)
                  : (short*)(smem + 65536 + wid * 32768);
  float* zb = (float*)Ast;                       // overlay, see ordering notes

  // ---- LDS fill: gather our 32 gate-columns from natural-ntile fragments ----
  {
    int c = lane & 15;
    for (int u = wid; u < 2 * KS; u += 2) {
      int tau = u >> ksh;
      int s = u & (KS - 1);
      int gate = tau * 2 + (c >> 3);
      int gc = gate * 1024 + u0 + (c & 7);
      int lanep = (lane & 48) + (gc & 15);
      const short* src = wf + ((size_t)(((gc >> 4) << ksh) + s) * 64 + lanep) * 8;
      g2l16(src, wlds + (tau * KS + s) * 512);
    }
  }
  __syncthreads();   // the only barrier; loop below is barrier-free

  const int g = wid;
  const int row16 = lane & 15;                   // MFMA A-row within group
  const int kb8 = (lane >> 4) << 3;              // MFMA A k-offset
  const int un = lane & 7;                       // gate unit (both pairs)
  const int r0 = lane >> 3;                      // gate row, pair 0 (0..7)
  const int r1 = 8 + (lane >> 3);                // gate row, pair 1 (8..15)
  float bias[4];
  {
    const float* bb = l1 ? b1 : b0;
#pragma unroll
    for (int g4 = 0; g4 < 4; g4++) bias[g4] = bb[g4 * 1024 + u0 + un];
  }
  float cst0 = 0.f, cst1 = 0.f;

  unsigned int* ownf = flags + ((l1 ? 2 : 0) + g) * 128;
  unsigned int* othf = flags + ((l1 ? 0 : 2) + g) * 128;
  unsigned int* myf = ownf + (wg & 127);

  auto poll = [&](unsigned own_t, unsigned oth_t) {
    if ((own_t | oth_t) == 0) return;
    const unsigned* po = ownf + lane * 2;
    const unsigned* pe = othf + lane * 2;
    for (int it = 0; it < (1 << 22); ++it) {
      u32x2 ov, ev;
      asm volatile(
          "global_load_dwordx2 %0, %2, off sc1\n\t"
          "global_load_dwordx2 %1, %3, off sc1\n\t"
          "s_waitcnt vmcnt(0)"
          : "=&v"(ov), "=&v"(ev)
          : "v"(po), "v"(pe)
          : "memory");
      if (__all(ov[0] >= own_t && ov[1] >= own_t &&
                ev[0] >= oth_t && ev[1] >= oth_t)) break;
      asm volatile("s_sleep 1");
    }
  };

  // transpose acc -> zb (wave-private), gates + state + h store for both rows
  auto finish = [&](f32x4 acc0, f32x4 acc1, float xz00, float xz01, float xz02,
                    float xz03, float xz10, float xz11, float xz12, float xz13,
                    short* hw, bool dump) {
#pragma unroll
    for (int r = 0; r < 4; r++) {
      zb[(((lane >> 4) << 2) + r) * 33 + (lane & 15)] = acc0[r];
      zb[(((lane >> 4) << 2) + r) * 33 + 16 + (lane & 15)] = acc1[r];
    }
    float z00 = zb[r0 * 33 + un] + bias[0] + xz00;
    float z01 = zb[r0 * 33 + 8 + un] + bias[1] + xz01;
    float z02 = zb[r0 * 33 + 16 + un] + bias[2] + xz02;
    float z03 = zb[r0 * 33 + 24 + un] + bias[3] + xz03;
    float z10 = zb[r1 * 33 + un] + bias[0] + xz10;
    float z11 = zb[r1 * 33 + 8 + un] + bias[1] + xz11;
    float z12 = zb[r1 * 33 + 16 + un] + bias[2] + xz12;
    float z13 = zb[r1 * 33 + 24 + un] + bias[3] + xz13;
    cst0 = sigm(z01) * cst0 + sigm(z00) * tanhf(z02);
    float hv0 = sigm(z03) * tanhf(cst0);
    cst1 = sigm(z11) * cst1 + sigm(z10) * tanhf(z12);
    float hv1 = sigm(z13) * tanhf(cst1);
    st2_sc1(hw + (g * 16 + r0) * 1024 + u0 + un, (unsigned)(unsigned short)f2bf(hv0));
    st2_sc1(hw + (g * 16 + r1) * 1024 + u0 + un, (unsigned)(unsigned short)f2bf(hv1));
    if (dump) {
      int oi0 = (g * 16 + r0) * 1024 + u0 + un;
      int oi1 = (g * 16 + r1) * 1024 + u0 + un;
      out[oi0] = hv0; out[32768 + oi0] = hv0; out[65536 + oi0] = cst0;
      out[oi1] = hv1; out[32768 + oi1] = hv1; out[65536 + oi1] = cst1;
    }
  };

  if (!l1) {
    // ---------------- layer 0: 512 steps, h0 ring depth 8 -------------------
    for (int t = 0; t < 512; ++t) {
      const unsigned short* xp0 = (const unsigned short*)xz0 +
          (size_t)((g * 16 + r0) * 512 + t) * 4096 + u0 + un;
      const unsigned short* xp1 = (const unsigned short*)xz0 +
          (size_t)((g * 16 + r1) * 512 + t) * 4096 + u0 + un;
      unsigned short x00 = xp0[0], x01 = xp0[1024], x02 = xp0[2048], x03 = xp0[3072];
      unsigned short x10 = xp1[0], x11 = xp1[1024], x12 = xp1[2048], x13 = xp1[3072];
      SBAR;
      poll((unsigned)t, (t >= 8) ? (unsigned)(t - 7) : 0u);
      SBAR;
      // stage all 32 ksteps of A into LDS (32KB), one drain, then compute
      const short* hs = h0ring + (size_t)((t - 1) & 7) * 32768 +
                        (g * 16 + row16) * 1024 + kb8;
#pragma unroll
      for (int q = 0; q < 32; q++) g2l16c(hs + q * 32, Ast + q * 512);
      SBAR; VM_DRAIN; SBAR;
      f32x4 acc0 = {}, acc1 = {};
#pragma unroll
      for (int q = 0; q < 32; q++) {
        bf16x8 a  = *(const bf16x8*)(Ast + q * 512 + lane * 8);
        bf16x8 b0 = *(const bf16x8*)(wlds + q * 512 + lane * 8);
        bf16x8 b1 = *(const bf16x8*)(wlds + (32 + q) * 512 + lane * 8);
        acc0 = __builtin_amdgcn_mfma_f32_16x16x32_bf16(a, b0, acc0, 0, 0, 0);
        acc1 = __builtin_amdgcn_mfma_f32_16x16x32_bf16(a, b1, acc1, 0, 0, 0);
      }
      finish(acc0, acc1, bf2f((short)x00), bf2f((short)x01), bf2f((short)x02),
             bf2f((short)x03), bf2f((short)x10), bf2f((short)x11),
             bf2f((short)x12), bf2f((short)x13),
             h0ring + (size_t)(t & 7) * 32768, false);
      VM_DRAIN;
      if (lane == 0) st4_sc1(myf, (unsigned)(t + 1));
    }
  } else {
    // ---------------- layer 1: 512 steps, h0(t) + h1(t-1) rings -------------
    // 16 phases x 4 ksteps (4KB), 4KB double-buffer, counted vmcnt(4) ladder.
    for (int t = 0; t < 512; ++t) {
      poll((unsigned)t, (unsigned)(t + 1));
      SBAR;
      const short* h0s = h0ring + (size_t)(t & 7) * 32768 +
                         (g * 16 + row16) * 1024 + kb8;
      const short* h1s = h1ring + (size_t)((t - 1) & 7) * 32768 +
                         (g * 16 + row16) * 1024 + kb8;
#define SRCQ(q) (((q) < 32) ? (h0s + (q) * 32) : (h1s + ((q) - 32) * 32))
#define STAGE4(p) do { \
      g2l16c(SRCQ((p) * 4 + 0), Ast + ((p) & 1) * 2048 + 0 * 512); \
      g2l16c(SRCQ((p) * 4 + 1), Ast + ((p) & 1) * 2048 + 1 * 512); \
      g2l16c(SRCQ((p) * 4 + 2), Ast + ((p) & 1) * 2048 + 2 * 512); \
      g2l16c(SRCQ((p) * 4 + 3), Ast + ((p) & 1) * 2048 + 3 * 512); \
} while (0)
      STAGE4(0); STAGE4(1);
      f32x4 acc0 = {}, acc1 = {};
#pragma unroll
      for (int p = 0; p < 16; p++) {
        if (p < 15) { SBAR; VM_W4; SBAR; } else { SBAR; VM_DRAIN; SBAR; }
#pragma unroll
        for (int j = 0; j < 4; j++) {
          int q = p * 4 + j;
          bf16x8 a  = *(const bf16x8*)(Ast + (p & 1) * 2048 + j * 512 + lane * 8);
          bf16x8 b0 = *(const bf16x8*)(wlds + q * 512 + lane * 8);
          bf16x8 b1 = *(const bf16x8*)(wlds + (64 + q) * 512 + lane * 8);
          acc0 = __builtin_amdgcn_mfma_f32_16x16x32_bf16(a, b0, acc0, 0, 0, 0);
          acc1 = __builtin_amdgcn_mfma_f32_16x16x32_bf16(a, b1, acc1, 0, 0, 0);
        }
        if (p < 14) STAGE4(p + 2);
      }
#undef STAGE4
#undef SRCQ
      finish(acc0, acc1, 0.f, 0.f, 0.f, 0.f, 0.f, 0.f, 0.f, 0.f,
             h1ring + (size_t)(t & 7) * 32768, t == 511);
      VM_DRAIN;
      if (lane == 0) st4_sc1(myf, (unsigned)(t + 1));
    }
  }
}

// ---------------------------------------------------------------------------
extern "C" void kernel_launch(void* const* d_in, const int* in_sizes, int n_in,
                              void* d_out, int out_size, void* d_ws, size_t ws_size,
                              hipStream_t stream) {
  const float* x  = (const float*)d_in[0];
  const float* W0 = (const float*)d_in[1];
  const float* U0 = (const float*)d_in[2];
  const float* b0 = (const float*)d_in[3];
  const float* W1 = (const float*)d_in[4];
  const float* U1 = (const float*)d_in[5];
  const float* b1 = (const float*)d_in[6];
  char* ws = (char*)d_ws;
  if (ws_size < WS_TOTAL) return;  // loud failure: no output written

  short* xz0p = (short*)(ws + XZ0_OFF);
  short* xfp  = (short*)(ws + XF_OFF);
  short* w0fp = (short*)(ws + W0F_OFF);
  short* u0fp = (short*)(ws + U0F_OFF);
  short* w1fp = (short*)(ws + W1F_OFF);
  short* ringp = (short*)(ws + RING_OFF);
  short* h1rp  = (short*)(ws + H1R_OFF);
  unsigned int* flagp = (unsigned int*)(ws + FLG_OFF);
  float* outp = (float*)d_out;

  (void)hipFuncSetAttribute((const void*)gemm_xw,
      hipFuncAttributeMaxDynamicSharedMemorySize, 65536);
  (void)hipFuncSetAttribute((const void*)lstm_persist,
      hipFuncAttributeMaxDynamicSharedMemorySize, 147456);

  hipLaunchKernelGGL(pack_x, dim3(8192), dim3(256), 0, stream, x, xfp);
  hipLaunchKernelGGL(pack_w, dim3(2048), dim3(256), 0, stream, W0, W0, 5, w0fp);
  hipLaunchKernelGGL(pack_w, dim3(2048), dim3(256), 0, stream, U0, U0, 5, u0fp);
  hipLaunchKernelGGL(pack_w, dim3(4096), dim3(256), 0, stream, W1, U1, 6, w1fp);
  hipLaunchKernelGGL(gemm_xw, dim3(4096), dim3(256), 65536, stream, xfp, w0fp, xz0p);

  // rings/flags overlay the xf region — zero them only after gemm consumed xf
  (void)hipMemsetAsync(ws + RING_OFF, 0, 524288 + 524288 + 4096, stream);

  const short* xz0c = xz0p;
  const short* u0fc = u0fp;
  const short* w1fc = w1fp;
  void* kargs[9] = {(void*)&xz0c, (void*)&u0fc, (void*)&w1fc,
                    (void*)&b0,   (void*)&b1,
                    (void*)&ringp, (void*)&h1rp, (void*)&flagp, (void*)&outp};
  (void)hipLaunchCooperativeKernel((const void*)lstm_persist, dim3(256), dim3(128),
                                   kargs, 147456u, stream);
}

// Round 11
// 3908.279 us; speedup vs baseline: 1.7128x; 1.7128x over previous
//
#include <hip/hip_runtime.h>
#include <cstdint>

// ---------------------------------------------------------------------------
// 2-layer LSTM encoder, B=32 T=512 F=H=1024.
// Phase 1: pack x, W0, U0, [W1;U1] into bf16 MFMA-fragment order.
// Phase 2: big GEMM xz0 = x @ W0 (bf16, fp32 accum), GATE-INTERLEAVED output
//          layout [row][unit][gate] so the persist kernel reads one dwordx2.
// Phase 3: persistent cooperative kernel, 256 WGs x 256 threads (4 waves),
//          R5 structure: G=2 serial group-minis, split-K across 4 waves,
//          per-group flags, sc1 LLC protocol. NEW: polls hidden in idle
//          waves (wave2 polls g1(t) during mini0's gates; wave3 polls
//          g0(t+1) during mini1's gates) -> straggler jitter off-path.
// ---------------------------------------------------------------------------

typedef __attribute__((ext_vector_type(8))) short bf16x8;
typedef __attribute__((ext_vector_type(4))) short s16x4;
typedef __attribute__((ext_vector_type(4))) float f32x4;
typedef __attribute__((ext_vector_type(2))) unsigned int u32x2;

// workspace layout (bytes)
#define XZ0_OFF   0ull                // 16384x4096 bf16   = 134217728
#define XF_OFF    134217728ull        // 16384x1024 bf16   =  33554432 (dead after gemm)
#define W0F_OFF   167772160ull        // 1024x4096  bf16   =   8388608
#define U0F_OFF   176160768ull        // 1024x4096  bf16   =   8388608
#define W1F_OFF   184549376ull        // 2048x4096  bf16   =  16777216
#define WS_TOTAL  201326592ull
// overlaid on XF after gemm_xw has consumed it:
#define RING_OFF  XF_OFF                 // 8 x 32x1024 bf16 = 524288
#define H1B_OFF   (XF_OFF + 524288ull)   // 2 x 32x1024 bf16 = 131072
#define FLG_OFF   (XF_OFF + 655360ull)   // 512 u32: [l0g0|l0g1|l1g0|l1g1]x128

__device__ __forceinline__ float bf2f(short s) {
  unsigned int u = ((unsigned int)(unsigned short)s) << 16;
  return __builtin_bit_cast(float, u);
}
__device__ __forceinline__ short f2bf(float f) {
  unsigned int u = __builtin_bit_cast(unsigned int, f);
  u = (u + 0x7fffu + ((u >> 16) & 1u)) >> 16;   // RTNE
  return (short)u;
}
__device__ __forceinline__ void g2l16(const void* g, void* l) {
  __builtin_amdgcn_global_load_lds(
      (const __attribute__((address_space(1))) unsigned int*)g,
      (__attribute__((address_space(3))) unsigned int*)l, 16, 0, 0);
}
__device__ __forceinline__ float sigm(float x) { return 1.f / (1.f + __expf(-x)); }

// agent-scope (LLC) access helpers — bypass per-XCD L2 staleness, no fences
__device__ __forceinline__ bf16x8 ld16_sc1(const short* p) {
  bf16x8 r;
  asm volatile("global_load_dwordx4 %0, %1, off sc1" : "=&v"(r) : "v"(p));
  return r;
}
__device__ __forceinline__ void st2_sc1(short* p, unsigned v) {
  asm volatile("global_store_short %0, %1, off sc1" :: "v"(p), "v"(v) : "memory");
}
__device__ __forceinline__ void st4_sc1(unsigned* p, unsigned v) {
  asm volatile("global_store_dword %0, %1, off sc1" :: "v"(p), "v"(v) : "memory");
}
#define VM_DRAIN asm volatile("s_waitcnt vmcnt(0)" ::: "memory")
#define SBAR __builtin_amdgcn_sched_barrier(0)

// ---------------------------------------------------------------------------
// pack_x: x fp32 [16384][1024] -> bf16 fragments [1024 mtiles][32 ksteps][64][8]
// ---------------------------------------------------------------------------
__global__ __launch_bounds__(256) void pack_x(const float* __restrict__ x,
                                              short* __restrict__ dst) {
  int gid = blockIdx.x * 256 + threadIdx.x;
  int lane = gid & 63;
  int unit = gid >> 6;
  int mtile = unit >> 5, kstep = unit & 31;
  int row = mtile * 16 + (lane & 15);
  int k0 = kstep * 32 + ((lane >> 4) << 3);
  const float* s = x + (size_t)row * 1024 + k0;
  bf16x8 v;
#pragma unroll
  for (int j = 0; j < 8; j++) v[j] = f2bf(s[j]);
  *(bf16x8*)(dst + (size_t)gid * 8) = v;
}

// ---------------------------------------------------------------------------
// pack_w: W fp32 [K][4096] -> bf16 fragments [256 ntiles][K/32][64][8]
// ---------------------------------------------------------------------------
__global__ __launch_bounds__(256) void pack_w(const float* __restrict__ src0,
                                              const float* __restrict__ src1,
                                              int ksh, short* __restrict__ dst) {
  int gid = blockIdx.x * 256 + threadIdx.x;
  int lane = gid & 63;
  int unit = gid >> 6;
  int ntile = unit >> ksh;
  int kstep = unit & ((1 << ksh) - 1);
  int col = ntile * 16 + (lane & 15);
  int k0 = kstep * 32 + ((lane >> 4) << 3);
  const float* s = (k0 < 1024) ? src0 : src1;
  int kk = k0 & 1023;
  bf16x8 v;
#pragma unroll
  for (int j = 0; j < 8; j++) v[j] = f2bf(s[(size_t)(kk + j) * 4096 + col]);
  *(bf16x8*)(dst + (size_t)gid * 8) = v;
}

// ---------------------------------------------------------------------------
// gemm_xw: xz0 = x @ W0 (bf16, fp32 accum), gate-interleaved epilogue:
// out index = row*4096 + (col&1023)*4 + (col>>10)   [row][unit][gate]
// ---------------------------------------------------------------------------
__global__ __launch_bounds__(256) void gemm_xw(const short* __restrict__ xf,
                                               const short* __restrict__ wf,
                                               short* __restrict__ outz) {
  extern __shared__ char smem[];

  int bid = blockIdx.x;
  int swz = (bid & 7) * 512 + (bid >> 3);
  int bn = swz >> 7;
  int bm = swz & 127;

  const int tid = threadIdx.x, wid = tid >> 6, lane = tid & 63;
  const int wm = wid >> 1, wn = wid & 1;
  f32x4 acc[4][4] = {};

  const short* xbase = xf + (size_t)(bm * 8) * 32 * 512;
  const short* wbase = wf + (size_t)(bn * 8) * 32 * 512;

  auto Abuf = [&](int buf) -> short* { return (short*)(smem + buf * 32768); };
  auto Bbuf = [&](int buf) -> short* { return (short*)(smem + 16384 + buf * 32768); };

  auto stage = [&](int buf, int kt) {
    short* A = Abuf(buf);
    short* B = Bbuf(buf);
#pragma unroll
    for (int i = 0; i < 4; i++) {
      int u = wid + 4 * i;
      int mt = u >> 1, ks = u & 1;
      int gk = kt * 2 + ks;
      g2l16(xbase + (size_t)(mt * 32 + gk) * 512 + lane * 8, A + u * 512);
      g2l16(wbase + (size_t)(mt * 32 + gk) * 512 + lane * 8, B + u * 512);
    }
  };

  stage(0, 0);
  __syncthreads();
  for (int kt = 0; kt < 16; kt++) {
    int buf = kt & 1;
    if (kt < 15) stage(buf ^ 1, kt + 1);
    const short* A = Abuf(buf) + (wm * 4) * 1024;
    const short* B = Bbuf(buf) + (wn * 4) * 1024;
#pragma unroll
    for (int ks = 0; ks < 2; ks++) {
      bf16x8 av[4], bv[4];
#pragma unroll
      for (int i = 0; i < 4; i++) av[i] = *(const bf16x8*)(A + (i * 2 + ks) * 512 + lane * 8);
#pragma unroll
      for (int j = 0; j < 4; j++) bv[j] = *(const bf16x8*)(B + (j * 2 + ks) * 512 + lane * 8);
#pragma unroll
      for (int i = 0; i < 4; i++)
#pragma unroll
        for (int j = 0; j < 4; j++)
          acc[i][j] = __builtin_amdgcn_mfma_f32_16x16x32_bf16(av[i], bv[j], acc[i][j], 0, 0, 0);
    }
    __syncthreads();
  }

  int rb = bm * 128 + wm * 64 + ((lane >> 4) << 2);
  int cb = bn * 128 + wn * 64 + (lane & 15);
#pragma unroll
  for (int i = 0; i < 4; i++)
#pragma unroll
    for (int j = 0; j < 4; j++)
#pragma unroll
      for (int r = 0; r < 4; r++) {
        size_t row = rb + i * 16 + r;
        int col = cb + j * 16;
        outz[row * 4096 + (size_t)(col & 1023) * 4 + (col >> 10)] = f2bf(acc[i][j][r]);
      }
}

// ---------------------------------------------------------------------------
// lstm_persist: R5 structure + hidden polls.
// flags: [0,128)=l0 g0, [128,256)=l0 g1, [256,384)=l1 g0, [384,512)=l1 g1
// ---------------------------------------------------------------------------
__global__ __launch_bounds__(256, 1) void lstm_persist(
    const short* __restrict__ xz0, const short* __restrict__ u0f,
    const short* __restrict__ w1u1f, const float* __restrict__ b0,
    const float* __restrict__ b1, short* __restrict__ h0ring,
    short* __restrict__ h1buf, unsigned int* __restrict__ flags,
    float* __restrict__ out) {
  extern __shared__ char smem[];
  short* wlds = (short*)smem;                  // weight fragments (64/128KB)
  float* red0 = (float*)(smem + 131072);       // 8KB reduce, group 0
  float* red1 = (float*)(smem + 139264);       // 8KB reduce, group 1

  const int wg = blockIdx.x;
  const int tid = threadIdx.x;
  const int wid = tid >> 6;
  const int lane = tid & 63;
  const bool l1 = (wg >= 128);
  const int u0 = (wg & 127) * 8;
  const int KS = l1 ? 64 : 32;
  const int ksh = l1 ? 6 : 5;
  const short* wf = l1 ? w1u1f : u0f;

  // ---- LDS fill: gather our 32 gate-columns from natural-ntile fragments ----
  {
    int c = lane & 15;
    for (int u = wid; u < 2 * KS; u += 4) {
      int tau = u >> ksh;
      int s = u & (KS - 1);
      int gate = tau * 2 + (c >> 3);
      int gc = gate * 1024 + u0 + (c & 7);
      int lanep = (lane & 48) + (gc & 15);
      const short* src = wf + ((size_t)(((gc >> 4) << ksh) + s) * 64 + lanep) * 8;
      g2l16(src, wlds + (tau * KS + s) * 512);
    }
  }
  __syncthreads();

  const int bl = (tid & 127) >> 3;          // group-local batch row (gates)
  const int uu = tid & 7;
  const int lrow = bl >> 2, reg = bl & 3;
  float bias[4];
  {
    const float* bb = l1 ? b1 : b0;
#pragma unroll
    for (int g = 0; g < 4; g++) bias[g] = bb[g * 1024 + u0 + uu];
  }

  unsigned int* ownbase = flags + (l1 ? 256 : 0);
  unsigned int* othbase = flags + (l1 ? 0 : 256);

  // wave-wide poll of group q's flags (caller guards which wave runs this)
  auto pollq = [&](int q, unsigned own_t, unsigned oth_t) {
    if ((own_t | oth_t) == 0) return;
    const unsigned* po = ownbase + q * 128 + lane * 2;
    const unsigned* pe = othbase + q * 128 + lane * 2;
    for (int it = 0; it < (1 << 22); ++it) {
      u32x2 ov, ev;
      asm volatile(
          "global_load_dwordx2 %0, %2, off sc1\n\t"
          "global_load_dwordx2 %1, %3, off sc1\n\t"
          "s_waitcnt vmcnt(0)"
          : "=&v"(ov), "=&v"(ev)
          : "v"(po), "v"(pe)
          : "memory");
      if (__all(ov[0] >= own_t && ov[1] >= own_t &&
                ev[0] >= oth_t && ev[1] >= oth_t)) break;
      asm volatile("s_sleep 1");
    }
  };

  // gates for one group (tid<128); h-row = g*16+bl
  auto gates1 = [&](const float* rd, s16x4 xv, float& cst, short* hw,
                    bool dump, int g) {
    float z[4];
#pragma unroll
    for (int g4 = 0; g4 < 4; g4++) {
      int tau = g4 >> 1;
      int lp = lrow * 16 + (g4 & 1) * 8 + uu;
      float s = bias[g4] + bf2f(xv[g4]);
#pragma unroll
      for (int w4 = 0; w4 < 4; w4++)
        s += rd[((w4 * 2 + tau) * 64 + lp) * 4 + reg];
      z[g4] = s;
    }
    float gi = sigm(z[0]);
    float gf = sigm(z[1]);
    float gg = tanhf(z[2]);
    float go = sigm(z[3]);
    cst = gf * cst + gi * gg;
    float hv = go * tanhf(cst);
    st2_sc1(hw + (g * 16 + bl) * 1024 + u0 + uu,
            (unsigned)(unsigned short)f2bf(hv));
    if (dump) {
      int oi = (g * 16 + bl) * 1024 + u0 + uu;
      out[oi] = hv;
      out[32768 + oi] = hv;
      out[65536 + oi] = cst;
    }
  };

  if (!l1) {
    // ---------------- layer 0: 512 steps, h0 ring depth 8 -------------------
    float c0 = 0.f, c1 = 0.f;
    auto mini = [&](int g, int t, float& cst) {
      // A loads (poll for this mini confirmed before last barrier)
      const short* ap = h0ring + (size_t)((t - 1) & 7) * 32768 +
                        (g * 16 + (lane & 15)) * 1024 + (wid << 8) +
                        ((lane >> 4) << 3);
      bf16x8 a[8];
#pragma unroll
      for (int ks = 0; ks < 8; ks++) a[ks] = ld16_sc1(ap + ks * 32);
      s16x4 xv = {0, 0, 0, 0};
      if (tid < 128)
        xv = *(const s16x4*)(xz0 +
              ((size_t)((g * 16 + bl) * 512 + t) * 1024 + u0 + uu) * 4);
      SBAR; VM_DRAIN; SBAR;
      f32x4 acc[2] = {};
#pragma unroll
      for (int ks = 0; ks < 8; ks++) {
        bf16x8 bt0 = *(const bf16x8*)(wlds + (wid * 8 + ks) * 512 + lane * 8);
        bf16x8 bt1 = *(const bf16x8*)(wlds + (32 + wid * 8 + ks) * 512 + lane * 8);
        acc[0] = __builtin_amdgcn_mfma_f32_16x16x32_bf16(a[ks], bt0, acc[0], 0, 0, 0);
        acc[1] = __builtin_amdgcn_mfma_f32_16x16x32_bf16(a[ks], bt1, acc[1], 0, 0, 0);
      }
      float* rd = g ? red1 : red0;
#pragma unroll
      for (int tau = 0; tau < 2; tau++)
        *(f32x4*)(rd + ((wid * 2 + tau) * 64 + lane) * 4) = acc[tau];
      __syncthreads();
      if (tid < 128) {
        gates1(rd, xv, cst, h0ring + (size_t)(t & 7) * 32768, false, g);
      } else if (wid == 2 && g == 0) {
        // hide poll for mini1(t): own g1 >= t, l1-consumed lag
        pollq(1, (unsigned)t, (t >= 8) ? (unsigned)(t - 7) : 0u);
      } else if (wid == 3 && g == 1 && t < 511) {
        // hide poll for mini0(t+1)
        pollq(0, (unsigned)(t + 1), (t + 1 >= 8) ? (unsigned)(t - 6) : 0u);
      }
      VM_DRAIN;
      __syncthreads();
      if (tid == 0) st4_sc1(ownbase + g * 128 + (wg & 127), (unsigned)(t + 1));
    };
    for (int t = 0; t < 512; ++t) { mini(0, t, c0); mini(1, t, c1); }
  } else {
    // ---------------- layer 1: 512 steps, h0 ring + h1 double buffer --------
    float c0 = 0.f, c1 = 0.f;
    if (wid == 3) pollq(0, 0u, 1u);      // prologue: mini0(0) needs l0 g0 >= 1
    __syncthreads();
    auto mini = [&](int g, int t, float& cst) {
      const short* Ab = (wid < 2) ? (h0ring + (size_t)(t & 7) * 32768)
                                  : (h1buf + (size_t)((t - 1) & 1) * 32768);
      const short* ap = Ab + (g * 16 + (lane & 15)) * 1024 + ((wid & 1) << 9) +
                        ((lane >> 4) << 3);
      bf16x8 a[2][8];
#pragma unroll
      for (int half = 0; half < 2; half++)
#pragma unroll
        for (int ks = 0; ks < 8; ks++)
          a[half][ks] = ld16_sc1(ap + half * 256 + ks * 32);
      SBAR; VM_DRAIN; SBAR;
      f32x4 acc[2] = {};
#pragma unroll
      for (int half = 0; half < 2; half++) {
        const int rb = wid * 16 + half * 8;
#pragma unroll
        for (int ks = 0; ks < 8; ks++) {
          bf16x8 bt0 = *(const bf16x8*)(wlds + (rb + ks) * 512 + lane * 8);
          bf16x8 bt1 = *(const bf16x8*)(wlds + (64 + rb + ks) * 512 + lane * 8);
          acc[0] = __builtin_amdgcn_mfma_f32_16x16x32_bf16(a[half][ks], bt0, acc[0], 0, 0, 0);
          acc[1] = __builtin_amdgcn_mfma_f32_16x16x32_bf16(a[half][ks], bt1, acc[1], 0, 0, 0);
        }
      }
      float* rd = g ? red1 : red0;
#pragma unroll
      for (int tau = 0; tau < 2; tau++)
        *(f32x4*)(rd + ((wid * 2 + tau) * 64 + lane) * 4) = acc[tau];
      __syncthreads();
      if (tid < 128) {
        s16x4 zv = {0, 0, 0, 0};
        gates1(rd, zv, cst, h1buf + (size_t)(t & 1) * 32768, t == 511, g);
      } else if (wid == 2 && g == 0) {
        // hide poll for mini1(t): own g1 >= t, l0 g1 >= t+1
        pollq(1, (unsigned)t, (unsigned)(t + 1));
      } else if (wid == 3 && g == 1 && t < 511) {
        // hide poll for mini0(t+1): own g0 >= t+1, l0 g0 >= t+2
        pollq(0, (unsigned)(t + 1), (unsigned)(t + 2));
      }
      VM_DRAIN;
      __syncthreads();
      if (tid == 0) st4_sc1(ownbase + g * 128 + (wg & 127), (unsigned)(t + 1));
    };
    for (int t = 0; t < 512; ++t) { mini(0, t, c0); mini(1, t, c1); }
  }
}

// ---------------------------------------------------------------------------
extern "C" void kernel_launch(void* const* d_in, const int* in_sizes, int n_in,
                              void* d_out, int out_size, void* d_ws, size_t ws_size,
                              hipStream_t stream) {
  const float* x  = (const float*)d_in[0];
  const float* W0 = (const float*)d_in[1];
  const float* U0 = (const float*)d_in[2];
  const float* b0 = (const float*)d_in[3];
  const float* W1 = (const float*)d_in[4];
  const float* U1 = (const float*)d_in[5];
  const float* b1 = (const float*)d_in[6];
  char* ws = (char*)d_ws;
  if (ws_size < WS_TOTAL) return;  // loud failure: no output written

  short* xz0p = (short*)(ws + XZ0_OFF);
  short* xfp  = (short*)(ws + XF_OFF);
  short* w0fp = (short*)(ws + W0F_OFF);
  short* u0fp = (short*)(ws + U0F_OFF);
  short* w1fp = (short*)(ws + W1F_OFF);
  short* ringp = (short*)(ws + RING_OFF);
  short* h1p   = (short*)(ws + H1B_OFF);
  unsigned int* flagp = (unsigned int*)(ws + FLG_OFF);
  float* outp = (float*)d_out;

  (void)hipFuncSetAttribute((const void*)gemm_xw,
      hipFuncAttributeMaxDynamicSharedMemorySize, 65536);
  (void)hipFuncSetAttribute((const void*)lstm_persist,
      hipFuncAttributeMaxDynamicSharedMemorySize, 147456);

  hipLaunchKernelGGL(pack_x, dim3(8192), dim3(256), 0, stream, x, xfp);
  hipLaunchKernelGGL(pack_w, dim3(2048), dim3(256), 0, stream, W0, W0, 5, w0fp);
  hipLaunchKernelGGL(pack_w, dim3(2048), dim3(256), 0, stream, U0, U0, 5, u0fp);
  hipLaunchKernelGGL(pack_w, dim3(4096), dim3(256), 0, stream, W1, U1, 6, w1fp);
  hipLaunchKernelGGL(gemm_xw, dim3(4096), dim3(256), 65536, stream, xfp, w0fp, xz0p);

  // ring/h1/flags overlay the xf region — zero them only after gemm consumed xf
  (void)hipMemsetAsync(ws + RING_OFF, 0, 524288 + 131072 + 4096, stream);

  const short* xz0c = xz0p;
  const short* u0fc = u0fp;
  const short* w1fc = w1fp;
  void* kargs[9] = {(void*)&xz0c, (void*)&u0fc, (void*)&w1fc,
                    (void*)&b0,   (void*)&b1,
                    (void*)&ringp, (void*)&h1p, (void*)&flagp, (void*)&outp};
  (void)hipLaunchCooperativeKernel((const void*)lstm_persist, dim3(256), dim3(256),
                                   kargs, 147456u, stream);
}